// Round 12
// baseline (588.678 us; speedup 1.0000x reference)
//
#include <hip/hip_runtime.h>

typedef unsigned short u16;
typedef unsigned int u32;
typedef __attribute__((ext_vector_type(8))) short bf16x8;
typedef __attribute__((ext_vector_type(4))) float f32x4;

#define NB 4
#define NVOX 8192
#define GD 50
#define CELLS 125000

// ---- workspace layout (bytes) ----
#define OWNER_OFF 0u            // int32[4*125000] = 2,000,000
#define STATS_OFF 2000000u      // f32[768]
#define WT1_OFF   2003072u      // bf16 27*64*128 frag-linear = 442,368
#define WT2_OFF   2445440u      // bf16 27*128*64 frag-linear = 442,368
#define VW2F_OFF  2887808u      // bf16 8*128*8  = 16,384
#define VW3F_OFF  2904192u      // bf16 16*128*8 = 32,768
#define FEATS_OFF 2936960u      // bf16 32768*128 = 8,388,608
#define Y1F_OFF   11325568u     // f32 4*125000*64 = 128,000,000  (end ~139MB)

#define S1_SUM 0
#define S1_SQ  64
#define SC1    128
#define SH1    192
#define S2_SUM 256
#define S2_SQ  384
#define SC2    512
#define SH2    640

__device__ __forceinline__ float bf2f(u16 v){ union{u32 u; float f;} x; x.u=((u32)v)<<16; return x.f; }
__device__ __forceinline__ u16 f2bf(float f){ union{u32 u; float f;} x; x.f=f; u32 r = x.u + 0x7fffu + ((x.u>>16)&1u); return (u16)(r>>16); }
__device__ __forceinline__ f32x4 fzero(){ f32x4 v; v[0]=0.f; v[1]=0.f; v[2]=0.f; v[3]=0.f; return v; }

// ---- weight re-layout ----
__global__ void k_wt_transform(const float* __restrict__ k1, const float* __restrict__ k2,
                               const float* __restrict__ W2, const float* __restrict__ W3,
                               u16* __restrict__ wt1, u16* __restrict__ wt2,
                               u16* __restrict__ vw2f, u16* __restrict__ vw3f) {
    int idx = blockIdx.x * 256 + threadIdx.x;
    if (idx < 221184) {
        {
            int j = idx & 7, co = (idx>>3)&63, kq = (idx>>9)&3, kc = (idx>>11)&3, s = idx>>13;
            int ci = kc*32 + kq*8 + j;
            wt1[idx] = f2bf(k1[(co*128 + ci)*27 + s]);
        }
        {
            int j = idx & 7, co = (idx>>3)&127, kq = (idx>>10)&3, kc = (idx>>12)&1, s = idx>>13;
            int ci = kc*32 + kq*8 + j;
            wt2[idx] = f2bf(k2[(co*64 + ci)*27 + s]);
        }
    }
    if (idx < 8192) {
        int j = idx & 7, n = (idx>>3)&127, q = idx>>10;
        vw2f[idx] = f2bf(W2[(q*8+j)*128 + n]);
    }
    if (idx < 16384) {
        int j = idx & 7, n = (idx>>3)&127, q = idx>>10;
        vw3f[idx] = f2bf(W3[(q*8+j)*128 + n]);
    }
}

// ---- duplicate resolution: last-write-wins == max n per cell ----
__global__ void k_owner(const int* __restrict__ coords, int* __restrict__ owner) {
    int v = blockIdx.x * 256 + threadIdx.x;
    if (v >= NB*NVOX) return;
    int b = v >> 13, n = v & (NVOX-1);
    int x = coords[v*3], y = coords[v*3+1], z = coords[v*3+2];
    atomicMax(&owner[b*CELLS + (x*GD + y)*GD + z], n);
}

// ---- VFE via MFMA: 4 voxels (128 points) per block -> compact feats ----
__global__ __launch_bounds__(256, 2) void k_vfe(
        const float* __restrict__ vf,
        const float* __restrict__ W1, const float* __restrict__ b1,
        const float* __restrict__ b2, const float* __restrict__ b3,
        const u16* __restrict__ vw2f, const u16* __restrict__ vw3f,
        u16* __restrict__ feats) {
    const int bid = blockIdx.x;
    const int t = threadIdx.x;
    const int w = t >> 6, lane = t & 63;
    const int lo = lane & 15, hi = lane >> 4;
    const int chgrp = w >> 1, pgrp = w & 1;

    __shared__ __align__(16) char pool[49152];
    u16* h1s = (u16*)pool;                 // [128][64] bf16 swizzled
    char* h2s = pool + 16384;              // [128][128] bf16 swizzled
    float* red = (float*)(pool + 16384);   // reuses h2s

    bf16x8 wa2[2][4], wa3[4][4];
    #pragma unroll
    for (int kk = 0; kk < 2; ++kk)
        #pragma unroll
        for (int cf = 0; cf < 4; ++cf)
            wa2[kk][cf] = *(const bf16x8*)(vw2f + (((kk*4+hi)*128) + chgrp*64 + cf*16 + lo)*8);
    #pragma unroll
    for (int kk = 0; kk < 4; ++kk)
        #pragma unroll
        for (int cf = 0; cf < 4; ++cf)
            wa3[kk][cf] = *(const bf16x8*)(vw3f + (((kk*4+hi)*128) + chgrp*64 + cf*16 + lo)*8);
    f32x4 bb2[4];
    #pragma unroll
    for (int cf = 0; cf < 4; ++cf)
        bb2[cf] = *(const f32x4*)(b2 + chgrp*64 + cf*16 + hi*4);

    {
        const int pt = t & 127, C0 = (t >> 7) * 32;
        f32x4 xv0 = *(const f32x4*)(vf + (size_t)(bid*128 + pt)*8);
        f32x4 xv1 = *(const f32x4*)(vf + (size_t)(bid*128 + pt)*8 + 4);
        float x[8] = {xv0[0],xv0[1],xv0[2],xv0[3],xv1[0],xv1[1],xv1[2],xv1[3]};
        float h[32];
        #pragma unroll
        for (int c = 0; c < 32; ++c) h[c] = b1[C0 + c];
        #pragma unroll
        for (int k = 0; k < 8; ++k) {
            float xk = x[k];
            #pragma unroll
            for (int c = 0; c < 32; ++c) h[c] += xk * W1[k*64 + C0 + c];
        }
        #pragma unroll
        for (int c8 = 0; c8 < 4; ++c8) {
            u16 d8[8];
            #pragma unroll
            for (int j = 0; j < 8; ++j) d8[j] = f2bf(fmaxf(h[c8*8 + j], 0.f));
            int slot = ((C0 >> 3) + c8) ^ (pt & 7);
            *(uint4*)(h1s + pt*64 + slot*8) = *(uint4*)d8;
        }
    }
    __syncthreads();

    f32x4 acc2[4][4];
    #pragma unroll
    for (int cf = 0; cf < 4; ++cf)
        #pragma unroll
        for (int pf = 0; pf < 4; ++pf) acc2[cf][pf] = fzero();
    #pragma unroll
    for (int kk = 0; kk < 2; ++kk) {
        bf16x8 bh[4];
        #pragma unroll
        for (int pf = 0; pf < 4; ++pf) {
            int pt = pgrp*64 + pf*16 + lo;
            bh[pf] = *(const bf16x8*)(h1s + pt*64 + (((kk*4+hi) ^ (pt&7)) << 3));
        }
        #pragma unroll
        for (int cf = 0; cf < 4; ++cf)
            #pragma unroll
            for (int pf = 0; pf < 4; ++pf)
                acc2[cf][pf] = __builtin_amdgcn_mfma_f32_16x16x32_bf16(wa2[kk][cf], bh[pf], acc2[cf][pf], 0, 0, 0);
    }
    #pragma unroll
    for (int cf = 0; cf < 4; ++cf) {
        #pragma unroll
        for (int pf = 0; pf < 4; ++pf) {
            int pt = pgrp*64 + pf*16 + lo;
            float v0 = fmaxf(acc2[cf][pf][0] + bb2[cf][0], 0.f);
            float v1 = fmaxf(acc2[cf][pf][1] + bb2[cf][1], 0.f);
            float v2 = fmaxf(acc2[cf][pf][2] + bb2[cf][2], 0.f);
            float v3 = fmaxf(acc2[cf][pf][3] + bb2[cf][3], 0.f);
            uint2 d;
            d.x = (u32)f2bf(v0) | ((u32)f2bf(v1) << 16);
            d.y = (u32)f2bf(v2) | ((u32)f2bf(v3) << 16);
            int s = (chgrp*8 + cf*2 + (hi>>1)) ^ (pt & 15);
            *(uint2*)(h2s + pt*256 + s*16 + (hi&1)*8) = d;
        }
    }
    __syncthreads();

    f32x4 acc3[4][4];
    #pragma unroll
    for (int cf = 0; cf < 4; ++cf)
        #pragma unroll
        for (int pf = 0; pf < 4; ++pf) acc3[cf][pf] = fzero();
    #pragma unroll
    for (int kk = 0; kk < 4; ++kk) {
        bf16x8 bh[4];
        #pragma unroll
        for (int pf = 0; pf < 4; ++pf) {
            int pt = pgrp*64 + pf*16 + lo;
            bh[pf] = *(const bf16x8*)(h2s + pt*256 + (((kk*4+hi) ^ (pt&15)) << 4));
        }
        #pragma unroll
        for (int cf = 0; cf < 4; ++cf)
            #pragma unroll
            for (int pf = 0; pf < 4; ++pf)
                acc3[cf][pf] = __builtin_amdgcn_mfma_f32_16x16x32_bf16(wa3[kk][cf], bh[pf], acc3[cf][pf], 0, 0, 0);
    }
    __syncthreads();

    #pragma unroll
    for (int vox01 = 0; vox01 < 2; ++vox01) {
        int vv = pgrp*2 + vox01;
        #pragma unroll
        for (int cf = 0; cf < 4; ++cf) {
            f32x4 mx;
            #pragma unroll
            for (int r = 0; r < 4; ++r)
                mx[r] = fmaxf(acc3[cf][vox01*2][r], acc3[cf][vox01*2+1][r]);
            int s4 = (cf*4 + hi) ^ lo;
            *(f32x4*)(red + vv*2048 + lo*128 + chgrp*64 + s4*4) = mx;
        }
    }
    __syncthreads();

    #pragma unroll
    for (int half = 0; half < 2; ++half) {
        int vv = (t >> 7) + half*2;
        int ch = t & 127;
        int cq = (ch & 63) >> 2, e = ch & 3, cg = ch >> 6;
        float m = -3.0e38f;
        #pragma unroll
        for (int lo2 = 0; lo2 < 16; ++lo2)
            m = fmaxf(m, red[vv*2048 + lo2*128 + cg*64 + ((cq ^ lo2) << 2) + e]);
        int gv = bid*4 + vv;
        feats[(size_t)gv*128 + ch] = f2bf(m + b3[ch]);
    }
}

// ---- conv1 as sparse scatter into LDS tile accumulator (atomic, barrier-free) ----
// Block = 2x2 xy-tile x 50 z. Halo voxels found by scanning owner over the
// 4x4 halo columns. Waves FREE-RUN over voxel chunks and 27 taps: per tap
// 16 MFMA (D[64co][16vox]) then per-lane masked ds_add_f32 into the LDS tile.
// LDS f32 atomics make cross-wave/tap collisions safe -> zero barriers in the
// hot loop -> A-loads of tap s+1 overlap MFMA of tap s, waves pipeline freely.
__global__ __launch_bounds__(256, 2) void k_conv1t(
        const u16* __restrict__ feats, const int* __restrict__ owner,
        const u16* __restrict__ wt1, float* __restrict__ y1f,
        float* __restrict__ stats) {
    const int tx = blockIdx.x, ty = blockIdx.y, b = blockIdx.z;
    const int t = threadIdx.x;
    const int w = t >> 6, lane = t & 63;
    const int lo = lane & 15, hi = lane >> 4;

    __shared__ __align__(16) float acc[200*68];   // 54,400 B (stride 68 spreads banks)
    __shared__ int list[800];
    __shared__ int cnt;

    if (t == 0) cnt = 0;
    for (int i = t; i < 200*17; i += 256)
        *(f32x4*)(acc + i*4) = fzero();
    __syncthreads();

    // build halo voxel list from owner map (entry: n | hxr<<13 | hyr<<15 | z<<17)
    for (int i = t; i < 800; i += 256) {
        int hxr = i / 200, r2 = i - hxr*200;
        int hyr = r2 / 50, z = r2 - hyr*50;
        int hx = 2*tx - 1 + hxr, hy = 2*ty - 1 + hyr;
        if (hx >= 0 && hx < GD && hy >= 0 && hy < GD) {
            int n = owner[b*CELLS + (hx*GD + hy)*GD + z];
            if (n >= 0) {
                int idx = atomicAdd(&cnt, 1);
                list[idx] = n | (hxr << 13) | (hyr << 15) | (z << 17);
            }
        }
    }
    __syncthreads();
    const int nch = (cnt + 15) >> 4;

    for (int c = w; c < nch; c += 4) {
        const int base = c * 16;
        int e = 0; bool lval = false;
        if (base + lo < cnt) { e = list[base + lo]; lval = true; }
        const int n = e & 8191, hxr = (e >> 13) & 3, hyr = (e >> 15) & 3, z = (e >> 17) & 63;
        bf16x8 bb[4];
        const u16* fsrc = feats + (size_t)(b*NVOX + n)*128 + hi*8;
        #pragma unroll
        for (int kc = 0; kc < 4; ++kc)
            bb[kc] = *(const bf16x8*)(fsrc + kc*32);
        #pragma unroll 3
        for (int s = 0; s < 27; ++s) {
            const int dx = s/9, r9 = s - dx*9, dy = r9/3, dz = r9 - dy*3;
            const int oxr = hxr - dx, oyr = hyr - dy, oz = z + 1 - dz;
            const bool val = lval && ((unsigned)oxr < 2u) && ((unsigned)oyr < 2u)
                                  && ((unsigned)oz < 50u);
            f32x4 dacc[4];
            #pragma unroll
            for (int nf = 0; nf < 4; ++nf) dacc[nf] = fzero();
            #pragma unroll
            for (int kc = 0; kc < 4; ++kc) {
                bf16x8 a[4];
                #pragma unroll
                for (int nf = 0; nf < 4; ++nf)
                    a[nf] = *(const bf16x8*)(wt1 + (size_t)(((s*4 + kc)*4 + hi)*64 + nf*16 + lo)*8);
                #pragma unroll
                for (int nf = 0; nf < 4; ++nf)
                    dacc[nf] = __builtin_amdgcn_mfma_f32_16x16x32_bf16(a[nf], bb[kc], dacc[nf], 0, 0, 0);
            }
            if (val) {
                float* p = acc + ((oxr*2 + oyr)*50 + oz)*68 + hi*4;
                #pragma unroll
                for (int nf = 0; nf < 4; ++nf) {
                    #pragma unroll
                    for (int r = 0; r < 4; ++r)
                        atomicAdd(p + nf*16 + r, dacc[nf][r]);
                }
            }
        }
    }
    __syncthreads();

    // epilogue: write tile to y1f + BN1 stats partials
    float s4[4] = {0.f,0.f,0.f,0.f}, q4[4] = {0.f,0.f,0.f,0.f};
    const int cq = t & 15;                 // channel quad: ch = cq*4+e (fixed/thread)
    for (int i = t; i < 3200; i += 256) {
        int cell = i >> 4;
        f32x4 v = *(const f32x4*)(acc + cell*68 + cq*4);
        int col = cell / 50, oz = cell - col*50;
        int ox = 2*tx + (col >> 1), oy = 2*ty + (col & 1);
        *(f32x4*)(y1f + (size_t)((b*GD + ox)*GD + oy)*3200 + oz*64 + cq*4) = v;
        #pragma unroll
        for (int e2 = 0; e2 < 4; ++e2) { s4[e2] += v[e2]; q4[e2] += v[e2]*v[e2]; }
    }
    __syncthreads();                       // acc reads done -> reuse as scratch
    #pragma unroll
    for (int e2 = 0; e2 < 4; ++e2) {
        acc[t*8 + e2]     = s4[e2];
        acc[t*8 + 4 + e2] = q4[e2];
    }
    __syncthreads();
    if (t < 128) {
        int isq = t >> 6, ch = t & 63, cq0 = ch >> 2, e2 = ch & 3;
        float sum = 0.f;
        #pragma unroll
        for (int k = 0; k < 16; ++k)
            sum += acc[(cq0 + 16*k)*8 + isq*4 + e2];
        atomicAdd(&stats[(isq ? S1_SQ : S1_SUM) + ch], sum);
    }
}

// ---- BN finalize ----
__global__ void k_finalize(float* __restrict__ stats, const float* __restrict__ g,
                           const float* __restrict__ be, int C, float cnt,
                           int st_off, int sc_off, int sh_off) {
    int t = threadIdx.x;
    if (t < C) {
        float mean = stats[st_off + t] / cnt;
        float var  = stats[st_off + C + t] / cnt - mean*mean;
        float inv  = rsqrtf(var + 1e-5f);
        stats[sc_off + t] = g[t]*inv;
        stats[sh_off + t] = be[t] - mean*g[t]*inv;
    }
}

// ---- conv2 via MFMA: 3x3x3, 64->128, stride 2, pad 1; BN1+ReLU fused in
// staging (reads f32 y1). B direct from L2; LDS 26.6KB -> 4 blocks/CU. ----
__global__ __launch_bounds__(256, 4) void k_conv2(
        const float* __restrict__ y1f, const u16* __restrict__ wt2,
        float* __restrict__ stats, float* __restrict__ out) {
    const int ox = blockIdx.x, oyp = blockIdx.y, b = blockIdx.z;
    const int t = threadIdx.x;
    const int w = t >> 6, lane = t & 63;
    const int col = w >> 1, nh = w & 1, lo = lane & 15, hi = lane >> 4;

    __shared__ __align__(16) char pool[26624];
    u16* in2 = (u16*)pool;                // [2][52][64] bf16, slot^=((z>>1)&7)
    float* red2 = (float*)(pool + 25600); // [256] f32
    red2[t] = 0.f;

    const float* sc1 = stats + SC1;
    const float* sh1 = stats + SH1;

    f32x4 acc[2][4];
    #pragma unroll
    for (int m=0;m<2;m++){ acc[m][0]=fzero(); acc[m][1]=fzero(); acc[m][2]=fzero(); acc[m][3]=fzero(); }

    const int oy = 2*oyp + col;
    for (int dxy = 0; dxy < 9; ++dxy) {
        int dx = dxy/3, dy = dxy - dx*3;
        int xi = 2*ox + dx - 1;
        bool okx = (xi >= 0) && (xi < GD);
        __syncthreads();
        for (int i = t; i < 832; i += 256) {
            int c = (i >= 416) ? 1 : 0;
            int cc = i - c*416;
            int z = cc >> 3, sl = cc & 7;
            int oyc = 2*oyp + c;
            int yi = 2*oyc + dy - 1;
            bool ok = okx && (oyc < 25) && (yi >= 0) && (yi < GD) && (z >= 1) && (z <= 50);
            u16 d8[8];
            if (ok) {
                const float* src = y1f + (size_t)((b*GD + xi)*GD + yi)*3200 + cc*8 - 64;
                f32x4 v0 = *(const f32x4*)src;
                f32x4 v1 = *(const f32x4*)(src + 4);
                #pragma unroll
                for (int j=0;j<4;j++) {
                    int ci = sl*8 + j;
                    d8[j] = f2bf(fmaxf(v0[j]*sc1[ci] + sh1[ci], 0.f));
                }
                #pragma unroll
                for (int j=0;j<4;j++) {
                    int ci = sl*8 + 4 + j;
                    d8[4+j] = f2bf(fmaxf(v1[j]*sc1[ci] + sh1[ci], 0.f));
                }
            } else {
                #pragma unroll
                for (int j=0;j<8;j++) d8[j] = 0;
            }
            *(uint4*)(in2 + (c*52 + z)*64 + ((sl ^ ((z>>1) & 7)) << 3)) = *(uint4*)d8;
        }
        __syncthreads();
        const u16* wsrc = wt2 + dxy*24576;
        #pragma unroll
        for (int dz = 0; dz < 3; ++dz) {
            #pragma unroll
            for (int kc = 0; kc < 2; ++kc) {
                bf16x8 a[2], bbw[4];
                #pragma unroll
                for (int mf = 0; mf < 2; ++mf) {
                    int z = 2*(mf*16 + lo) + dz; z = (z > 51) ? 51 : z;
                    a[mf] = *(const bf16x8*)(in2 + (col*52 + z)*64 + (((kc*4 + hi) ^ ((z>>1) & 7)) << 3));
                }
                #pragma unroll
                for (int nf = 0; nf < 4; ++nf)
                    bbw[nf] = *(const bf16x8*)(wsrc + (((dz*2 + kc)*4 + hi)*128 + (nh*4 + nf)*16 + lo)*8);
                #pragma unroll
                for (int mf = 0; mf < 2; ++mf) {
                    #pragma unroll
                    for (int nf = 0; nf < 4; ++nf)
                        acc[mf][nf] = __builtin_amdgcn_mfma_f32_16x16x32_bf16(a[mf], bbw[nf], acc[mf][nf], 0, 0, 0);
                }
            }
        }
    }
    __syncthreads();
    float* trans = (float*)pool;      // [2][128][25] f32 = 25,600 B (in2 dead)
    if (oy < 25) {
        #pragma unroll
        for (int nf = 0; nf < 4; ++nf) {
            float s = 0.f, q = 0.f;
            int co = (nh*4 + nf)*16 + lo;
            #pragma unroll
            for (int mf = 0; mf < 2; ++mf) {
                #pragma unroll
                for (int r = 0; r < 4; ++r) {
                    int o = mf*16 + hi*4 + r;
                    if (o < 25) {
                        float vv = acc[mf][nf][r];
                        trans[(col*128 + co)*25 + o] = vv;
                        s += vv; q += vv*vv;
                    }
                }
            }
            atomicAdd(&red2[co], s);
            atomicAdd(&red2[128 + co], q);
        }
    }
    __syncthreads();
    if (t < 128) {
        atomicAdd(&stats[S2_SUM + t], red2[t]);
        atomicAdd(&stats[S2_SQ  + t], red2[128 + t]);
    }
    for (int i = t; i < 6400; i += 256) {
        int c = i / 3200; int r = i - c*3200;
        int co = r / 25;  int oz = r - co*25;
        int oyc = 2*oyp + c;
        if (oyc < 25)
            out[((size_t)(b*128 + co)*625 + ox*25 + oyc)*25 + oz] = trans[(c*128 + co)*25 + oz];
    }
}

// ---- BN2 + ReLU in place on d_out ----
__global__ void k_bnrelu2(float* __restrict__ out, const float* __restrict__ stats) {
    int idx = blockIdx.x*256 + threadIdx.x;
    if (idx >= 8000000) return;
    int co = (idx / 15625) & 127;
    float v = out[idx];
    out[idx] = fmaxf(v*stats[SC2 + co] + stats[SH2 + co], 0.f);
}

extern "C" void kernel_launch(void* const* d_in, const int* in_sizes, int n_in,
                              void* d_out, int out_size, void* d_ws, size_t ws_size,
                              hipStream_t stream) {
    const float* vf     = (const float*)d_in[0];
    const int*   coords = (const int*)  d_in[1];
    const float* W1 = (const float*)d_in[2];
    const float* b1 = (const float*)d_in[3];
    const float* W2 = (const float*)d_in[4];
    const float* b2 = (const float*)d_in[5];
    const float* W3 = (const float*)d_in[6];
    const float* b3 = (const float*)d_in[7];
    const float* k1 = (const float*)d_in[8];
    const float* g1 = (const float*)d_in[9];
    const float* be1= (const float*)d_in[10];
    const float* k2 = (const float*)d_in[11];
    const float* g2 = (const float*)d_in[12];
    const float* be2= (const float*)d_in[13];

    char* ws = (char*)d_ws;
    int*   owner = (int*)  (ws + OWNER_OFF);
    float* stats = (float*)(ws + STATS_OFF);
    u16*   wt1   = (u16*)  (ws + WT1_OFF);
    u16*   wt2   = (u16*)  (ws + WT2_OFF);
    u16*   vw2f  = (u16*)  (ws + VW2F_OFF);
    u16*   vw3f  = (u16*)  (ws + VW3F_OFF);
    u16*   feats = (u16*)  (ws + FEATS_OFF);
    float* y1f   = (float*)(ws + Y1F_OFF);
    float* out   = (float*)d_out;

    hipMemsetAsync(owner, 0xFF, (size_t)NB*CELLS*4, stream);
    hipMemsetAsync(stats, 0, 768*4, stream);

    k_wt_transform<<<864, 256, 0, stream>>>(k1, k2, W2, W3, wt1, wt2, vw2f, vw3f);
    k_owner<<<(NB*NVOX+255)/256, 256, 0, stream>>>(coords, owner);
    k_vfe<<<NB*NVOX/4, 256, 0, stream>>>(vf, W1, b1, b2, b3, vw2f, vw3f, feats);
    k_conv1t<<<dim3(25,25,NB), 256, 0, stream>>>(feats, owner, wt1, y1f, stats);
    k_finalize<<<1, 64, 0, stream>>>(stats, g1, be1, 64, 500000.f, S1_SUM, SC1, SH1);
    k_conv2<<<dim3(25,13,NB), 256, 0, stream>>>(y1f, wt2, stats, out);
    k_finalize<<<1, 128, 0, stream>>>(stats, g2, be2, 128, 62500.f, S2_SUM, SC2, SH2);
    k_bnrelu2<<<(8000000+255)/256, 256, 0, stream>>>(out, stats);
}

// Round 13
// 425.867 us; speedup vs baseline: 1.3823x; 1.3823x over previous
//
#include <hip/hip_runtime.h>

typedef unsigned short u16;
typedef unsigned int u32;
typedef __attribute__((ext_vector_type(8))) short bf16x8;
typedef __attribute__((ext_vector_type(4))) float f32x4;

#define NB 4
#define NVOX 8192
#define GD 50
#define CELLS 125000

// ---- workspace layout (bytes) ----
#define OWNER_OFF 0u            // int32[4*125000] = 2,000,000
#define STATS_OFF 2000000u      // f32[768]
#define WT1_OFF   2003072u      // bf16 27*64*128 frag-linear = 442,368
#define WT2_OFF   2445440u      // bf16 27*128*64 frag-linear = 442,368
#define VW2F_OFF  2887808u      // bf16 8*128*8  = 16,384
#define VW3F_OFF  2904192u      // bf16 16*128*8 = 32,768
#define FEATS_OFF 2936960u      // bf16 32768*128 = 8,388,608
#define Y1F_OFF   11325568u     // f32 4*125000*64 = 128,000,000  (end ~139MB)

#define S1_SUM 0
#define S1_SQ  64
#define SC1    128
#define SH1    192
#define S2_SUM 256
#define S2_SQ  384
#define SC2    512
#define SH2    640

__device__ __forceinline__ float bf2f(u16 v){ union{u32 u; float f;} x; x.u=((u32)v)<<16; return x.f; }
__device__ __forceinline__ u16 f2bf(float f){ union{u32 u; float f;} x; x.f=f; u32 r = x.u + 0x7fffu + ((x.u>>16)&1u); return (u16)(r>>16); }
__device__ __forceinline__ f32x4 fzero(){ f32x4 v; v[0]=0.f; v[1]=0.f; v[2]=0.f; v[3]=0.f; return v; }

// ---- weight re-layout ----
__global__ void k_wt_transform(const float* __restrict__ k1, const float* __restrict__ k2,
                               const float* __restrict__ W2, const float* __restrict__ W3,
                               u16* __restrict__ wt1, u16* __restrict__ wt2,
                               u16* __restrict__ vw2f, u16* __restrict__ vw3f) {
    int idx = blockIdx.x * 256 + threadIdx.x;
    if (idx < 221184) {
        {
            int j = idx & 7, co = (idx>>3)&63, kq = (idx>>9)&3, kc = (idx>>11)&3, s = idx>>13;
            int ci = kc*32 + kq*8 + j;
            wt1[idx] = f2bf(k1[(co*128 + ci)*27 + s]);
        }
        {
            int j = idx & 7, co = (idx>>3)&127, kq = (idx>>10)&3, kc = (idx>>12)&1, s = idx>>13;
            int ci = kc*32 + kq*8 + j;
            wt2[idx] = f2bf(k2[(co*64 + ci)*27 + s]);
        }
    }
    if (idx < 8192) {
        int j = idx & 7, n = (idx>>3)&127, q = idx>>10;
        vw2f[idx] = f2bf(W2[(q*8+j)*128 + n]);
    }
    if (idx < 16384) {
        int j = idx & 7, n = (idx>>3)&127, q = idx>>10;
        vw3f[idx] = f2bf(W3[(q*8+j)*128 + n]);
    }
}

// ---- duplicate resolution: last-write-wins == max n per cell ----
__global__ void k_owner(const int* __restrict__ coords, int* __restrict__ owner) {
    int v = blockIdx.x * 256 + threadIdx.x;
    if (v >= NB*NVOX) return;
    int b = v >> 13, n = v & (NVOX-1);
    int x = coords[v*3], y = coords[v*3+1], z = coords[v*3+2];
    atomicMax(&owner[b*CELLS + (x*GD + y)*GD + z], n);
}

// ---- VFE via MFMA: 4 voxels (128 points) per block -> compact feats ----
__global__ __launch_bounds__(256, 2) void k_vfe(
        const float* __restrict__ vf,
        const float* __restrict__ W1, const float* __restrict__ b1,
        const float* __restrict__ b2, const float* __restrict__ b3,
        const u16* __restrict__ vw2f, const u16* __restrict__ vw3f,
        u16* __restrict__ feats) {
    const int bid = blockIdx.x;
    const int t = threadIdx.x;
    const int w = t >> 6, lane = t & 63;
    const int lo = lane & 15, hi = lane >> 4;
    const int chgrp = w >> 1, pgrp = w & 1;

    __shared__ __align__(16) char pool[49152];
    u16* h1s = (u16*)pool;                 // [128][64] bf16 swizzled
    char* h2s = pool + 16384;              // [128][128] bf16 swizzled
    float* red = (float*)(pool + 16384);   // reuses h2s

    bf16x8 wa2[2][4], wa3[4][4];
    #pragma unroll
    for (int kk = 0; kk < 2; ++kk)
        #pragma unroll
        for (int cf = 0; cf < 4; ++cf)
            wa2[kk][cf] = *(const bf16x8*)(vw2f + (((kk*4+hi)*128) + chgrp*64 + cf*16 + lo)*8);
    #pragma unroll
    for (int kk = 0; kk < 4; ++kk)
        #pragma unroll
        for (int cf = 0; cf < 4; ++cf)
            wa3[kk][cf] = *(const bf16x8*)(vw3f + (((kk*4+hi)*128) + chgrp*64 + cf*16 + lo)*8);
    f32x4 bb2[4];
    #pragma unroll
    for (int cf = 0; cf < 4; ++cf)
        bb2[cf] = *(const f32x4*)(b2 + chgrp*64 + cf*16 + hi*4);

    {
        const int pt = t & 127, C0 = (t >> 7) * 32;
        f32x4 xv0 = *(const f32x4*)(vf + (size_t)(bid*128 + pt)*8);
        f32x4 xv1 = *(const f32x4*)(vf + (size_t)(bid*128 + pt)*8 + 4);
        float x[8] = {xv0[0],xv0[1],xv0[2],xv0[3],xv1[0],xv1[1],xv1[2],xv1[3]};
        float h[32];
        #pragma unroll
        for (int c = 0; c < 32; ++c) h[c] = b1[C0 + c];
        #pragma unroll
        for (int k = 0; k < 8; ++k) {
            float xk = x[k];
            #pragma unroll
            for (int c = 0; c < 32; ++c) h[c] += xk * W1[k*64 + C0 + c];
        }
        #pragma unroll
        for (int c8 = 0; c8 < 4; ++c8) {
            u16 d8[8];
            #pragma unroll
            for (int j = 0; j < 8; ++j) d8[j] = f2bf(fmaxf(h[c8*8 + j], 0.f));
            int slot = ((C0 >> 3) + c8) ^ (pt & 7);
            *(uint4*)(h1s + pt*64 + slot*8) = *(uint4*)d8;
        }
    }
    __syncthreads();

    f32x4 acc2[4][4];
    #pragma unroll
    for (int cf = 0; cf < 4; ++cf)
        #pragma unroll
        for (int pf = 0; pf < 4; ++pf) acc2[cf][pf] = fzero();
    #pragma unroll
    for (int kk = 0; kk < 2; ++kk) {
        bf16x8 bh[4];
        #pragma unroll
        for (int pf = 0; pf < 4; ++pf) {
            int pt = pgrp*64 + pf*16 + lo;
            bh[pf] = *(const bf16x8*)(h1s + pt*64 + (((kk*4+hi) ^ (pt&7)) << 3));
        }
        #pragma unroll
        for (int cf = 0; cf < 4; ++cf)
            #pragma unroll
            for (int pf = 0; pf < 4; ++pf)
                acc2[cf][pf] = __builtin_amdgcn_mfma_f32_16x16x32_bf16(wa2[kk][cf], bh[pf], acc2[cf][pf], 0, 0, 0);
    }
    #pragma unroll
    for (int cf = 0; cf < 4; ++cf) {
        #pragma unroll
        for (int pf = 0; pf < 4; ++pf) {
            int pt = pgrp*64 + pf*16 + lo;
            float v0 = fmaxf(acc2[cf][pf][0] + bb2[cf][0], 0.f);
            float v1 = fmaxf(acc2[cf][pf][1] + bb2[cf][1], 0.f);
            float v2 = fmaxf(acc2[cf][pf][2] + bb2[cf][2], 0.f);
            float v3 = fmaxf(acc2[cf][pf][3] + bb2[cf][3], 0.f);
            uint2 d;
            d.x = (u32)f2bf(v0) | ((u32)f2bf(v1) << 16);
            d.y = (u32)f2bf(v2) | ((u32)f2bf(v3) << 16);
            int s = (chgrp*8 + cf*2 + (hi>>1)) ^ (pt & 15);
            *(uint2*)(h2s + pt*256 + s*16 + (hi&1)*8) = d;
        }
    }
    __syncthreads();

    f32x4 acc3[4][4];
    #pragma unroll
    for (int cf = 0; cf < 4; ++cf)
        #pragma unroll
        for (int pf = 0; pf < 4; ++pf) acc3[cf][pf] = fzero();
    #pragma unroll
    for (int kk = 0; kk < 4; ++kk) {
        bf16x8 bh[4];
        #pragma unroll
        for (int pf = 0; pf < 4; ++pf) {
            int pt = pgrp*64 + pf*16 + lo;
            bh[pf] = *(const bf16x8*)(h2s + pt*256 + (((kk*4+hi) ^ (pt&15)) << 4));
        }
        #pragma unroll
        for (int cf = 0; cf < 4; ++cf)
            #pragma unroll
            for (int pf = 0; pf < 4; ++pf)
                acc3[cf][pf] = __builtin_amdgcn_mfma_f32_16x16x32_bf16(wa3[kk][cf], bh[pf], acc3[cf][pf], 0, 0, 0);
    }
    __syncthreads();

    #pragma unroll
    for (int vox01 = 0; vox01 < 2; ++vox01) {
        int vv = pgrp*2 + vox01;
        #pragma unroll
        for (int cf = 0; cf < 4; ++cf) {
            f32x4 mx;
            #pragma unroll
            for (int r = 0; r < 4; ++r)
                mx[r] = fmaxf(acc3[cf][vox01*2][r], acc3[cf][vox01*2+1][r]);
            int s4 = (cf*4 + hi) ^ lo;
            *(f32x4*)(red + vv*2048 + lo*128 + chgrp*64 + s4*4) = mx;
        }
    }
    __syncthreads();

    #pragma unroll
    for (int half = 0; half < 2; ++half) {
        int vv = (t >> 7) + half*2;
        int ch = t & 127;
        int cq = (ch & 63) >> 2, e = ch & 3, cg = ch >> 6;
        float m = -3.0e38f;
        #pragma unroll
        for (int lo2 = 0; lo2 < 16; ++lo2)
            m = fmaxf(m, red[vv*2048 + lo2*128 + cg*64 + ((cq ^ lo2) << 2) + e]);
        int gv = bid*4 + vv;
        feats[(size_t)gv*128 + ch] = f2bf(m + b3[ch]);
    }
}

// ---- conv1 as sparse scatter, wave-private channel-quadrant accumulators ----
// Block = 2x2 xy-tile x 25 z (z-split, grid 25x25x8). Wave w owns channels
// [16w,16w+16) and a private LDS region -> NO barriers, NO atomics in the hot
// loop. All waves process all voxels: per tap s, 1 A-frag/kc (wt1 quadrant
// slice) x register-cached B-frags (feats, 2 chunks) -> 4 MFMA + one masked
// b128 RMW per chunk. Within an instruction lanes hit distinct cells (one
// owner per cell); across waves channels are disjoint. Deterministic.
__global__ __launch_bounds__(256, 3) void k_conv1t(
        const u16* __restrict__ feats, const int* __restrict__ owner,
        const u16* __restrict__ wt1, float* __restrict__ y1f,
        float* __restrict__ stats) {
    const int tx = blockIdx.x, ty = blockIdx.y;
    const int b = blockIdx.z >> 1, h = blockIdx.z & 1;
    const int z0 = h*25;
    const int t = threadIdx.x;
    const int w = t >> 6, lane = t & 63;
    const int lo = lane & 15, hi = lane >> 4;

    __shared__ __align__(16) float acc[4*100*20];   // 32,000 B, per-wave regions of 2000 f32
    __shared__ int list[432];
    __shared__ int cnt;

    if (t == 0) cnt = 0;
    for (int i = t; i < 2000; i += 256)
        *(f32x4*)(acc + i*4) = fzero();
    __syncthreads();

    // scan 4x4 halo columns, z in [z0-1, z0+25] (27 rows) -> voxel list
    for (int i = t; i < 432; i += 256) {
        int hxr = i / 108, r2 = i - hxr*108;
        int hyr = r2 / 27, zz = r2 - hyr*27;
        int z = z0 - 1 + zz;
        int hx = 2*tx - 1 + hxr, hy = 2*ty - 1 + hyr;
        if (hx >= 0 && hx < GD && hy >= 0 && hy < GD && z >= 0 && z < GD) {
            int n = owner[b*CELLS + (hx*GD + hy)*GD + z];
            if (n >= 0) {
                int idx = atomicAdd(&cnt, 1);
                list[idx] = n | (hxr << 13) | (hyr << 15) | (z << 17);
            }
        }
    }
    __syncthreads();
    const int C = cnt;
    float* accw = acc + w*2000;

    for (int g = 0; g*32 < C; ++g) {
        int e0 = 0, e1 = 0; bool v0 = false, v1 = false;
        { int i0 = g*32 + lo;      if (i0 < C) { e0 = list[i0]; v0 = true; } }
        { int i1 = g*32 + 16 + lo; if (i1 < C) { e1 = list[i1]; v1 = true; } }
        const u16* f0 = feats + (size_t)(b*NVOX + (e0 & 8191))*128 + hi*8;
        const u16* f1 = feats + (size_t)(b*NVOX + (e1 & 8191))*128 + hi*8;
        bf16x8 bb0[4], bb1[4];
        #pragma unroll
        for (int kc = 0; kc < 4; ++kc) bb0[kc] = *(const bf16x8*)(f0 + kc*32);
        #pragma unroll
        for (int kc = 0; kc < 4; ++kc) bb1[kc] = *(const bf16x8*)(f1 + kc*32);
        const int hx0 = (e0>>13)&3, hy0 = (e0>>15)&3, zz0 = (e0>>17)&63;
        const int hx1 = (e1>>13)&3, hy1 = (e1>>15)&3, zz1 = (e1>>17)&63;
        const bool two = (g*32 + 16 < C);   // wave-uniform

        #pragma unroll 1
        for (int s = 0; s < 27; ++s) {
            const int dx = s/9, r9 = s - dx*9, dy = r9/3, dz = r9 - dy*3;
            bf16x8 a[4];
            #pragma unroll
            for (int kc = 0; kc < 4; ++kc)
                a[kc] = *(const bf16x8*)(wt1 + (size_t)((s*4 + kc)*4 + hi)*512 + (w*16 + lo)*8);
            {   // chunk 0
                int oxr = hx0 - dx, oyr = hy0 - dy, ozl = zz0 + 1 - dz - z0;
                bool val = v0 && ((unsigned)oxr < 2u) && ((unsigned)oyr < 2u)
                              && ((unsigned)ozl < 25u);
                f32x4 d = fzero();
                #pragma unroll
                for (int kc = 0; kc < 4; ++kc)
                    d = __builtin_amdgcn_mfma_f32_16x16x32_bf16(a[kc], bb0[kc], d, 0, 0, 0);
                if (val) {
                    float* p = accw + ((oxr*2 + oyr)*25 + ozl)*20 + hi*4;
                    f32x4 o = *(f32x4*)p;
                    o[0] += d[0]; o[1] += d[1]; o[2] += d[2]; o[3] += d[3];
                    *(f32x4*)p = o;
                }
            }
            if (two) {  // chunk 1
                int oxr = hx1 - dx, oyr = hy1 - dy, ozl = zz1 + 1 - dz - z0;
                bool val = v1 && ((unsigned)oxr < 2u) && ((unsigned)oyr < 2u)
                              && ((unsigned)ozl < 25u);
                f32x4 d = fzero();
                #pragma unroll
                for (int kc = 0; kc < 4; ++kc)
                    d = __builtin_amdgcn_mfma_f32_16x16x32_bf16(a[kc], bb1[kc], d, 0, 0, 0);
                if (val) {
                    float* p = accw + ((oxr*2 + oyr)*25 + ozl)*20 + hi*4;
                    f32x4 o = *(f32x4*)p;
                    o[0] += d[0]; o[1] += d[1]; o[2] += d[2]; o[3] += d[3];
                    *(f32x4*)p = o;
                }
            }
        }
    }
    __syncthreads();

    // epilogue: write tile to y1f + BN1 stats partials
    float s4[4] = {0.f,0.f,0.f,0.f}, q4[4] = {0.f,0.f,0.f,0.f};
    const int cq = t & 15;                 // channel quad: ch = cq*4+e
    for (int i = t; i < 1600; i += 256) {
        int cell = i >> 4;                 // 0..99
        f32x4 v = *(const f32x4*)(acc + (cq>>2)*2000 + cell*20 + (cq&3)*4);
        int col = cell / 25, ozl = cell - col*25;
        int ox = 2*tx + (col >> 1), oy = 2*ty + (col & 1);
        *(f32x4*)(y1f + (size_t)((b*GD + ox)*GD + oy)*3200 + (z0 + ozl)*64 + cq*4) = v;
        #pragma unroll
        for (int e2 = 0; e2 < 4; ++e2) { s4[e2] += v[e2]; q4[e2] += v[e2]*v[e2]; }
    }
    __syncthreads();                       // acc reads done -> reuse as scratch
    #pragma unroll
    for (int e2 = 0; e2 < 4; ++e2) {
        acc[t*8 + e2]     = s4[e2];
        acc[t*8 + 4 + e2] = q4[e2];
    }
    __syncthreads();
    if (t < 128) {
        int isq = t >> 6, ch = t & 63, cq0 = ch >> 2, e2 = ch & 3;
        float sum = 0.f;
        #pragma unroll
        for (int k = 0; k < 16; ++k)
            sum += acc[(cq0 + 16*k)*8 + isq*4 + e2];
        atomicAdd(&stats[(isq ? S1_SQ : S1_SUM) + ch], sum);
    }
}

// ---- BN finalize ----
__global__ void k_finalize(float* __restrict__ stats, const float* __restrict__ g,
                           const float* __restrict__ be, int C, float cnt,
                           int st_off, int sc_off, int sh_off) {
    int t = threadIdx.x;
    if (t < C) {
        float mean = stats[st_off + t] / cnt;
        float var  = stats[st_off + C + t] / cnt - mean*mean;
        float inv  = rsqrtf(var + 1e-5f);
        stats[sc_off + t] = g[t]*inv;
        stats[sh_off + t] = be[t] - mean*g[t]*inv;
    }
}

// ---- conv2 via MFMA: 3x3x3, 64->128, stride 2, pad 1; BN1+ReLU fused in
// staging (reads f32 y1). B direct from L2; LDS 26.6KB -> 4 blocks/CU. ----
__global__ __launch_bounds__(256, 4) void k_conv2(
        const float* __restrict__ y1f, const u16* __restrict__ wt2,
        float* __restrict__ stats, float* __restrict__ out) {
    const int ox = blockIdx.x, oyp = blockIdx.y, b = blockIdx.z;
    const int t = threadIdx.x;
    const int w = t >> 6, lane = t & 63;
    const int col = w >> 1, nh = w & 1, lo = lane & 15, hi = lane >> 4;

    __shared__ __align__(16) char pool[26624];
    u16* in2 = (u16*)pool;                // [2][52][64] bf16, slot^=((z>>1)&7)
    float* red2 = (float*)(pool + 25600); // [256] f32
    red2[t] = 0.f;

    const float* sc1 = stats + SC1;
    const float* sh1 = stats + SH1;

    f32x4 acc[2][4];
    #pragma unroll
    for (int m=0;m<2;m++){ acc[m][0]=fzero(); acc[m][1]=fzero(); acc[m][2]=fzero(); acc[m][3]=fzero(); }

    const int oy = 2*oyp + col;
    for (int dxy = 0; dxy < 9; ++dxy) {
        int dx = dxy/3, dy = dxy - dx*3;
        int xi = 2*ox + dx - 1;
        bool okx = (xi >= 0) && (xi < GD);
        __syncthreads();
        for (int i = t; i < 832; i += 256) {
            int c = (i >= 416) ? 1 : 0;
            int cc = i - c*416;
            int z = cc >> 3, sl = cc & 7;
            int oyc = 2*oyp + c;
            int yi = 2*oyc + dy - 1;
            bool ok = okx && (oyc < 25) && (yi >= 0) && (yi < GD) && (z >= 1) && (z <= 50);
            u16 d8[8];
            if (ok) {
                const float* src = y1f + (size_t)((b*GD + xi)*GD + yi)*3200 + cc*8 - 64;
                f32x4 v0 = *(const f32x4*)src;
                f32x4 v1 = *(const f32x4*)(src + 4);
                #pragma unroll
                for (int j=0;j<4;j++) {
                    int ci = sl*8 + j;
                    d8[j] = f2bf(fmaxf(v0[j]*sc1[ci] + sh1[ci], 0.f));
                }
                #pragma unroll
                for (int j=0;j<4;j++) {
                    int ci = sl*8 + 4 + j;
                    d8[4+j] = f2bf(fmaxf(v1[j]*sc1[ci] + sh1[ci], 0.f));
                }
            } else {
                #pragma unroll
                for (int j=0;j<8;j++) d8[j] = 0;
            }
            *(uint4*)(in2 + (c*52 + z)*64 + ((sl ^ ((z>>1) & 7)) << 3)) = *(uint4*)d8;
        }
        __syncthreads();
        const u16* wsrc = wt2 + dxy*24576;
        #pragma unroll
        for (int dz = 0; dz < 3; ++dz) {
            #pragma unroll
            for (int kc = 0; kc < 2; ++kc) {
                bf16x8 a[2], bbw[4];
                #pragma unroll
                for (int mf = 0; mf < 2; ++mf) {
                    int z = 2*(mf*16 + lo) + dz; z = (z > 51) ? 51 : z;
                    a[mf] = *(const bf16x8*)(in2 + (col*52 + z)*64 + (((kc*4 + hi) ^ ((z>>1) & 7)) << 3));
                }
                #pragma unroll
                for (int nf = 0; nf < 4; ++nf)
                    bbw[nf] = *(const bf16x8*)(wsrc + (((dz*2 + kc)*4 + hi)*128 + (nh*4 + nf)*16 + lo)*8);
                #pragma unroll
                for (int mf = 0; mf < 2; ++mf) {
                    #pragma unroll
                    for (int nf = 0; nf < 4; ++nf)
                        acc[mf][nf] = __builtin_amdgcn_mfma_f32_16x16x32_bf16(a[mf], bbw[nf], acc[mf][nf], 0, 0, 0);
                }
            }
        }
    }
    __syncthreads();
    float* trans = (float*)pool;      // [2][128][25] f32 = 25,600 B (in2 dead)
    if (oy < 25) {
        #pragma unroll
        for (int nf = 0; nf < 4; ++nf) {
            float s = 0.f, q = 0.f;
            int co = (nh*4 + nf)*16 + lo;
            #pragma unroll
            for (int mf = 0; mf < 2; ++mf) {
                #pragma unroll
                for (int r = 0; r < 4; ++r) {
                    int o = mf*16 + hi*4 + r;
                    if (o < 25) {
                        float vv = acc[mf][nf][r];
                        trans[(col*128 + co)*25 + o] = vv;
                        s += vv; q += vv*vv;
                    }
                }
            }
            atomicAdd(&red2[co], s);
            atomicAdd(&red2[128 + co], q);
        }
    }
    __syncthreads();
    if (t < 128) {
        atomicAdd(&stats[S2_SUM + t], red2[t]);
        atomicAdd(&stats[S2_SQ  + t], red2[128 + t]);
    }
    for (int i = t; i < 6400; i += 256) {
        int c = i / 3200; int r = i - c*3200;
        int co = r / 25;  int oz = r - co*25;
        int oyc = 2*oyp + c;
        if (oyc < 25)
            out[((size_t)(b*128 + co)*625 + ox*25 + oyc)*25 + oz] = trans[(c*128 + co)*25 + oz];
    }
}

// ---- BN2 + ReLU in place on d_out ----
__global__ void k_bnrelu2(float* __restrict__ out, const float* __restrict__ stats) {
    int idx = blockIdx.x*256 + threadIdx.x;
    if (idx >= 8000000) return;
    int co = (idx / 15625) & 127;
    float v = out[idx];
    out[idx] = fmaxf(v*stats[SC2 + co] + stats[SH2 + co], 0.f);
}

extern "C" void kernel_launch(void* const* d_in, const int* in_sizes, int n_in,
                              void* d_out, int out_size, void* d_ws, size_t ws_size,
                              hipStream_t stream) {
    const float* vf     = (const float*)d_in[0];
    const int*   coords = (const int*)  d_in[1];
    const float* W1 = (const float*)d_in[2];
    const float* b1 = (const float*)d_in[3];
    const float* W2 = (const float*)d_in[4];
    const float* b2 = (const float*)d_in[5];
    const float* W3 = (const float*)d_in[6];
    const float* b3 = (const float*)d_in[7];
    const float* k1 = (const float*)d_in[8];
    const float* g1 = (const float*)d_in[9];
    const float* be1= (const float*)d_in[10];
    const float* k2 = (const float*)d_in[11];
    const float* g2 = (const float*)d_in[12];
    const float* be2= (const float*)d_in[13];

    char* ws = (char*)d_ws;
    int*   owner = (int*)  (ws + OWNER_OFF);
    float* stats = (float*)(ws + STATS_OFF);
    u16*   wt1   = (u16*)  (ws + WT1_OFF);
    u16*   wt2   = (u16*)  (ws + WT2_OFF);
    u16*   vw2f  = (u16*)  (ws + VW2F_OFF);
    u16*   vw3f  = (u16*)  (ws + VW3F_OFF);
    u16*   feats = (u16*)  (ws + FEATS_OFF);
    float* y1f   = (float*)(ws + Y1F_OFF);
    float* out   = (float*)d_out;

    hipMemsetAsync(owner, 0xFF, (size_t)NB*CELLS*4, stream);
    hipMemsetAsync(stats, 0, 768*4, stream);

    k_wt_transform<<<864, 256, 0, stream>>>(k1, k2, W2, W3, wt1, wt2, vw2f, vw3f);
    k_owner<<<(NB*NVOX+255)/256, 256, 0, stream>>>(coords, owner);
    k_vfe<<<NB*NVOX/4, 256, 0, stream>>>(vf, W1, b1, b2, b3, vw2f, vw3f, feats);
    k_conv1t<<<dim3(25,25,NB*2), 256, 0, stream>>>(feats, owner, wt1, y1f, stats);
    k_finalize<<<1, 64, 0, stream>>>(stats, g1, be1, 64, 500000.f, S1_SUM, SC1, SH1);
    k_conv2<<<dim3(25,13,NB), 256, 0, stream>>>(y1f, wt2, stats, out);
    k_finalize<<<1, 128, 0, stream>>>(stats, g2, be2, 128, 62500.f, S2_SUM, SC2, SH2);
    k_bnrelu2<<<(8000000+255)/256, 256, 0, stream>>>(out, stats);
}